// Round 6
// baseline (192.440 us; speedup 1.0000x reference)
//
#include <hip/hip_runtime.h>
#include <hip/hip_bf16.h>

#define B_ 4
#define S_ 4096
#define D_ 1024
#define H_ 64
#define SCALE_ 0.125f
#define WP_ 1056   // padded wq row stride (shorts)
#define SP_ 4224   // padded qT row stride (shorts)

typedef __attribute__((ext_vector_type(8))) short bf16x8;
typedef __attribute__((ext_vector_type(4))) float f32x4;

// round-to-nearest-even f32 -> bf16 (finite inputs)
static __device__ __forceinline__ short f2bf(float f) {
    unsigned u = __builtin_bit_cast(unsigned, f);
    u += 0x7fffu + ((u >> 16) & 1u);
    return (short)(u >> 16);
}

// ---------------------------------------------------------------------------
// winit: wq f32 -> bf16 into padded [64][WP_] layout.
// ---------------------------------------------------------------------------
__global__ __launch_bounds__(256) void winit_kernel(
    const float* __restrict__ wq, short* __restrict__ wqb)
{
    const int i   = blockIdx.x * 256 + threadIdx.x;
    const int row = i >> 7;
    const int col = (i & 127) * 8;
    const float* s = wq + (size_t)row * D_ + col;
    bf16x8 v;
#pragma unroll
    for (int e = 0; e < 8; ++e) v[e] = f2bf(s[e]);
    *(bf16x8*)(wqb + (size_t)row * WP_ + col) = v;
}

// ---------------------------------------------------------------------------
// qproj: q = x @ wq^T (bf16 MFMA). Block = 16 output rows, 4 waves = 4
// K-quarters. x staged via 16 FULLY-COALESCED 1KB wave-loads (f32x4/lane,
// one row per step). wq B-frags from padded wqb (L2-hot). LDS combine;
// writes q and channel-padded qT.
// ---------------------------------------------------------------------------
__global__ __launch_bounds__(256) void qproj_mfma(
    const float* __restrict__ x, const short* __restrict__ wqb,
    short* __restrict__ q, short* __restrict__ qT)
{
    __shared__ short xs[4][16][264];  // per-wave bf16 A chunk
    __shared__ float cs[4][16][68];   // per-wave partial C
    __shared__ short qs[16][68];      // combined tile for qT transpose

    const int tid  = threadIdx.x;
    const int wave = tid >> 6;        // = K-quarter
    const int lane = tid & 63;
    const int quad = lane >> 4;
    const int lr   = lane & 15;
    const int row0 = blockIdx.x * 16;

    // stage 16 rows x 256 cols f32 -> bf16; each step = one row, wave reads
    // 1KB contiguous (16 lines), writes 8B/lane contiguous to LDS.
    {
        const float* xp = x + (size_t)row0 * D_ + wave * 256 + lane * 4;
#pragma unroll
        for (int s = 0; s < 16; ++s) {
            const f32x4 v = *(const f32x4*)(xp + (size_t)s * D_);
            unsigned long long pk = 0;
#pragma unroll
            for (int e = 0; e < 4; ++e)
                pk |= (unsigned long long)(unsigned short)f2bf(v[e]) << (16 * e);
            *(unsigned long long*)&xs[wave][s][lane * 4] = pk;
        }
    }
    __syncthreads();

    f32x4 acc[4];
#pragma unroll
    for (int nb = 0; nb < 4; ++nb) acc[nb] = (f32x4){0.f, 0.f, 0.f, 0.f};

    const short* wp = wqb + (size_t)lr * WP_ + wave * 256 + quad * 8;
#pragma unroll
    for (int t = 0; t < 8; ++t) {
        const bf16x8 a = *(const bf16x8*)&xs[wave][lr][t * 32 + quad * 8];
#pragma unroll
        for (int nb = 0; nb < 4; ++nb) {
            const bf16x8 bb = *(const bf16x8*)(wp + (size_t)(nb * 16) * WP_ + t * 32);
            acc[nb] = __builtin_amdgcn_mfma_f32_16x16x32_bf16(a, bb, acc[nb], 0, 0, 0);
        }
    }

#pragma unroll
    for (int nb = 0; nb < 4; ++nb)
#pragma unroll
        for (int i = 0; i < 4; ++i)
            cs[wave][quad * 4 + i][nb * 16 + lr] = acc[nb][i];
    __syncthreads();

    const int r  = tid >> 4;
    const int c4 = (tid & 15) * 4;
    unsigned long long pv = 0;
#pragma unroll
    for (int j = 0; j < 4; ++j) {
        const float s = cs[0][r][c4 + j] + cs[1][r][c4 + j]
                      + cs[2][r][c4 + j] + cs[3][r][c4 + j];
        pv |= (unsigned long long)(unsigned short)f2bf(s) << (16 * j);
    }
    *(unsigned long long*)(q + (size_t)(row0 + r) * H_ + c4) = pv;
    *(unsigned long long*)&qs[r][c4] = pv;
    __syncthreads();

    const int hh = tid >> 2;
    const int sj = (tid & 3) * 4;
    const int b  = row0 >> 12;
    const int sl = row0 & (S_ - 1);
    unsigned long long w = 0;
#pragma unroll
    for (int e = 0; e < 4; ++e)
        w |= (unsigned long long)(unsigned short)qs[sj + e][hh] << (16 * e);
    *(unsigned long long*)(qT + ((size_t)b * H_ + hh) * SP_ + sl + sj) = w;
}

// ---------------------------------------------------------------------------
// flash v3: k = v = q, bf16 MFMA, no online max. Block = 1024 thr (16 waves)
// per 64 Q-rows; wave w: qset=w&3 (16 Q-rows), ks=w>>2 (1024 K-rows).
// Per k-iter all 4 K-slices' kt (K rows) + vt (V^T rows) tiles staged to LDS
// by dedicated waves with COALESCED uint4 loads, register-prefetched across
// the barrier. Tile granules XOR-swizzled (no padding) -> conflict-free
// ds_read_b128 B-frags. 4-way K-split combined in reused LDS; no atomics.
// ---------------------------------------------------------------------------
__global__ __launch_bounds__(1024) void flash_mfma(
    const short* __restrict__ q, const short* __restrict__ qT,
    float* __restrict__ out)
{
    __shared__ short tiles[2][4][64][64];  // [kt|vt][slice][row][granule-swizzled]
    __shared__ short pl[16][16][72];       // per-wave P
    __shared__ float lpart[4][64];

    const int tid  = threadIdx.x;
    const int w    = tid >> 6;        // wave 0..15
    const int lane = tid & 63;
    const int quad = lane >> 4;
    const int lr   = lane & 15;
    const int b    = blockIdx.y;
    const int q0   = blockIdx.x * 64;
    const int qset = w & 3;
    const int ks   = w >> 2;
    const short* qb  = q  + (size_t)b * S_ * H_;
    const short* qTb = qT + (size_t)b * H_ * SP_;

    // ---- staging role: waves 0-7 -> kt slices, waves 8-15 -> vt slices ----
    const int st_kt = (w < 8) ? 1 : 0;
    const int wk    = st_kt ? w : (w - 8);
    const int ss    = wk >> 1;          // slice this wave stages
    const int half  = wk & 1;           // which 32 rows
    short* stile = &tiles[st_kt ? 0 : 1][ss][0][0];

    int   wroff[4];                     // LDS dest (shorts), swizzled
    const short* gsrc[4];               // global src pointers
#pragma unroll
    for (int j = 0; j < 4; ++j) {
        const int row = half * 32 + j * 8 + (lane >> 3);
        const int g   = lane & 7;
        wroff[j] = row * 64 + ((g ^ (row & 7)) * 8);
        if (st_kt)  // contiguous: (ss*1024 + row)*64 + g*8  ==  linear in (j,lane)
            gsrc[j] = qb + (size_t)(ss * 1024) * 64 + half * 2048 + j * 512 + lane * 8;
        else        // vt: 8 rows x 128B per load, stride SP_
            gsrc[j] = qTb + (size_t)row * SP_ + ss * 1024 + g * 8;
    }
    const int gstep = st_kt ? 64 * 64 : 64;   // shorts per k-iter

    // ---- Q A-fragments (resident) ----
    bf16x8 qa[2];
    {
        const short* qr = qb + (size_t)(q0 + qset * 16 + lr) * H_;
        qa[0] = *(const bf16x8*)(qr + quad * 8);
        qa[1] = *(const bf16x8*)(qr + 32 + quad * 8);
    }

    f32x4 o[4];
#pragma unroll
    for (int nb = 0; nb < 4; ++nb) o[nb] = (f32x4){0.f, 0.f, 0.f, 0.f};
    float l4[4] = {0.f, 0.f, 0.f, 0.f};

    const short* kt_s = &tiles[0][ks][0][0];
    const short* vt_s = &tiles[1][ks][0][0];

    uint4 pre[4];
#pragma unroll
    for (int j = 0; j < 4; ++j) pre[j] = *(const uint4*)gsrc[j];

    for (int kk = 0; kk < 1024; kk += 64) {
        __syncthreads();               // previous tiles fully consumed
#pragma unroll
        for (int j = 0; j < 4; ++j) *(uint4*)(stile + wroff[j]) = pre[j];
        if (kk + 64 < 1024) {
#pragma unroll
            for (int j = 0; j < 4; ++j) {
                gsrc[j] += gstep;
                pre[j] = *(const uint4*)gsrc[j];   // in flight during compute
            }
        }
        __syncthreads();               // staging visible

        // ---- S = Q K^T ----
        f32x4 s[4];
#pragma unroll
        for (int nb = 0; nb < 4; ++nb) s[nb] = (f32x4){0.f, 0.f, 0.f, 0.f};
#pragma unroll
        for (int h = 0; h < 2; ++h) {
#pragma unroll
            for (int nb = 0; nb < 4; ++nb) {
                const int row = nb * 16 + lr;
                const bf16x8 bk = *(const bf16x8*)(kt_s + row * 64 + (((h * 4 + quad) ^ (row & 7)) * 8));
                s[nb] = __builtin_amdgcn_mfma_f32_16x16x32_bf16(qa[h], bk, s[nb], 0, 0, 0);
            }
        }

        // ---- P = exp(s*scale); row partials; P -> LDS ----
#pragma unroll
        for (int nb = 0; nb < 4; ++nb)
#pragma unroll
            for (int i = 0; i < 4; ++i) {
                const float p = __expf(s[nb][i] * SCALE_);
                l4[i] += p;
                pl[w][quad * 4 + i][nb * 16 + lr] = f2bf(p);
            }

        // ---- O += P @ V ----
#pragma unroll
        for (int h = 0; h < 2; ++h) {
            const bf16x8 pa = *(const bf16x8*)&pl[w][lr][h * 32 + quad * 8];
#pragma unroll
            for (int nb = 0; nb < 4; ++nb) {
                const int row = nb * 16 + lr;
                const bf16x8 bv = *(const bf16x8*)(vt_s + row * 64 + (((h * 4 + quad) ^ (row & 7)) * 8));
                o[nb] = __builtin_amdgcn_mfma_f32_16x16x32_bf16(pa, bv, o[nb], 0, 0, 0);
            }
        }
    }

    // ---- per-wave row-sum reduce; stash l ----
#pragma unroll
    for (int i = 0; i < 4; ++i) {
        float v = l4[i];
        v += __shfl_xor(v, 1, 64);
        v += __shfl_xor(v, 2, 64);
        v += __shfl_xor(v, 4, 64);
        v += __shfl_xor(v, 8, 64);
        if (lr == 0) lpart[ks][qset * 16 + quad * 4 + i] = v;
    }
    __syncthreads();                   // all tile reads done -> reuse as opart

    float* opart = (float*)&tiles[0][0][0][0];   // [4 ks][64 row][64 col] f32
#pragma unroll
    for (int nb = 0; nb < 4; ++nb)
#pragma unroll
        for (int i = 0; i < 4; ++i)
            opart[((size_t)ks * 64 + qset * 16 + quad * 4 + i) * 64 + nb * 16 + lr] = o[nb][i];
    __syncthreads();

    // ---- combine 4 K-slices, normalize, write ----
    const int r  = tid >> 4;           // 0..63
    const int c4 = (tid & 15) * 4;
    const float linv = 1.0f / (lpart[0][r] + lpart[1][r] + lpart[2][r] + lpart[3][r]);
    f32x4 res;
#pragma unroll
    for (int j = 0; j < 4; ++j)
        res[j] = (opart[(0 * 64 + (size_t)r) * 64 + c4 + j]
                + opart[(1 * 64 + (size_t)r) * 64 + c4 + j]
                + opart[(2 * 64 + (size_t)r) * 64 + c4 + j]
                + opart[(3 * 64 + (size_t)r) * 64 + c4 + j]) * linv;
    *(f32x4*)(out + ((size_t)b * S_ + q0 + r) * H_ + c4) = res;
}

extern "C" void kernel_launch(void* const* d_in, const int* in_sizes, int n_in,
                              void* d_out, int out_size, void* d_ws, size_t ws_size,
                              hipStream_t stream) {
    const float* x  = (const float*)d_in[0];   // [4,4096,1024] f32
    const float* wq = (const float*)d_in[1];   // [64,1024] f32
    float* out = (float*)d_out;                // [4,4096,64] f32

    short* qbuf = (short*)d_ws;                                        // 2 MiB
    short* qT   = (short*)((char*)d_ws + (2u << 20));                  // ~2.06 MiB
    short* wqb  = (short*)((char*)d_ws + (2u << 20) + (size_t)B_ * H_ * SP_ * 2);

    winit_kernel<<<dim3(32), dim3(256), 0, stream>>>(wq, wqb);
    qproj_mfma<<<dim3((B_ * S_) / 16), dim3(256), 0, stream>>>(x, wqb, qbuf, qT);
    flash_mfma<<<dim3(S_ / 64, B_), dim3(1024), 0, stream>>>(qbuf, qT, out);
}

// Round 7
// 138.554 us; speedup vs baseline: 1.3889x; 1.3889x over previous
//
#include <hip/hip_runtime.h>
#include <hip/hip_bf16.h>

#define B_ 4
#define S_ 4096
#define D_ 1024
#define H_ 64
#define SCALE_ 0.125f
#define WP_ 1056   // padded wq row stride (shorts)
#define SP_ 4224   // padded qT row stride (shorts)

typedef __attribute__((ext_vector_type(8))) short bf16x8;
typedef __attribute__((ext_vector_type(4))) short bf16x4;
typedef __attribute__((ext_vector_type(4))) float f32x4;

// round-to-nearest-even f32 -> bf16 (finite inputs)
static __device__ __forceinline__ short f2bf(float f) {
    unsigned u = __builtin_bit_cast(unsigned, f);
    u += 0x7fffu + ((u >> 16) & 1u);
    return (short)(u >> 16);
}

// ---------------------------------------------------------------------------
// winit: wq f32 -> bf16 into padded [64][WP_] layout.
// ---------------------------------------------------------------------------
__global__ __launch_bounds__(256) void winit_kernel(
    const float* __restrict__ wq, short* __restrict__ wqb)
{
    const int i   = blockIdx.x * 256 + threadIdx.x;
    const int row = i >> 7;
    const int col = (i & 127) * 8;
    const float* s = wq + (size_t)row * D_ + col;
    bf16x8 v;
#pragma unroll
    for (int e = 0; e < 8; ++e) v[e] = f2bf(s[e]);
    *(bf16x8*)(wqb + (size_t)row * WP_ + col) = v;
}

// ---------------------------------------------------------------------------
// qproj: q = x @ wq^T (bf16 MFMA). Block = 16 output rows, 4 waves = 4
// K-quarters, coalesced 1KB wave-loads for x, LDS combine, writes q and
// channel-padded qT. (unchanged from r6 — not the bottleneck)
// ---------------------------------------------------------------------------
__global__ __launch_bounds__(256) void qproj_mfma(
    const float* __restrict__ x, const short* __restrict__ wqb,
    short* __restrict__ q, short* __restrict__ qT)
{
    __shared__ short xs[4][16][264];
    __shared__ float cs[4][16][68];
    __shared__ short qs[16][68];

    const int tid  = threadIdx.x;
    const int wave = tid >> 6;
    const int lane = tid & 63;
    const int quad = lane >> 4;
    const int lr   = lane & 15;
    const int row0 = blockIdx.x * 16;

    {
        const float* xp = x + (size_t)row0 * D_ + wave * 256 + lane * 4;
#pragma unroll
        for (int s = 0; s < 16; ++s) {
            const f32x4 v = *(const f32x4*)(xp + (size_t)s * D_);
            unsigned long long pk = 0;
#pragma unroll
            for (int e = 0; e < 4; ++e)
                pk |= (unsigned long long)(unsigned short)f2bf(v[e]) << (16 * e);
            *(unsigned long long*)&xs[wave][s][lane * 4] = pk;
        }
    }
    __syncthreads();

    f32x4 acc[4];
#pragma unroll
    for (int nb = 0; nb < 4; ++nb) acc[nb] = (f32x4){0.f, 0.f, 0.f, 0.f};

    const short* wp = wqb + (size_t)lr * WP_ + wave * 256 + quad * 8;
#pragma unroll
    for (int t = 0; t < 8; ++t) {
        const bf16x8 a = *(const bf16x8*)&xs[wave][lr][t * 32 + quad * 8];
#pragma unroll
        for (int nb = 0; nb < 4; ++nb) {
            const bf16x8 bb = *(const bf16x8*)(wp + (size_t)(nb * 16) * WP_ + t * 32);
            acc[nb] = __builtin_amdgcn_mfma_f32_16x16x32_bf16(a, bb, acc[nb], 0, 0, 0);
        }
    }

#pragma unroll
    for (int nb = 0; nb < 4; ++nb)
#pragma unroll
        for (int i = 0; i < 4; ++i)
            cs[wave][quad * 4 + i][nb * 16 + lr] = acc[nb][i];
    __syncthreads();

    const int r  = tid >> 4;
    const int c4 = (tid & 15) * 4;
    unsigned long long pv = 0;
#pragma unroll
    for (int j = 0; j < 4; ++j) {
        const float s = cs[0][r][c4 + j] + cs[1][r][c4 + j]
                      + cs[2][r][c4 + j] + cs[3][r][c4 + j];
        pv |= (unsigned long long)(unsigned short)f2bf(s) << (16 * j);
    }
    *(unsigned long long*)(q + (size_t)(row0 + r) * H_ + c4) = pv;
    *(unsigned long long*)&qs[r][c4] = pv;
    __syncthreads();

    const int hh = tid >> 2;
    const int sj = (tid & 3) * 4;
    const int b  = row0 >> 12;
    const int sl = row0 & (S_ - 1);
    unsigned long long w = 0;
#pragma unroll
    for (int e = 0; e < 4; ++e)
        w |= (unsigned long long)(unsigned short)qs[sj + e][hh] << (16 * e);
    *(unsigned long long*)(qT + ((size_t)b * H_ + hh) * SP_ + sl + sj) = w;
}

// ---------------------------------------------------------------------------
// flash v4: transposed-score dataflow. Per 64-K tile:
//   S^T = K·Q^T  (A = K rows from kt LDS, B = resident Q regs)
//   -> exp lands as P^T rows: lane holds P^T[k=mt*16+quad*4+i][q=lr]
//   -> 4x ds_write_b64 to plT[q][k]; PV B-frag = plT[lr][quad*8..] b128
//   O = V^T·P^T-style: A = vt rows (h), B = P^T  => D[h-row][q-col]
// l (row sums) accumulate per lane (fixed q=lr), 2 shuffles to finish.
// Split-K over blockIdx.z -> f32 partials in ws, combined by combine_kernel.
// ---------------------------------------------------------------------------
__global__ __launch_bounds__(256, 4) void flash_mfma(
    const short* __restrict__ q, const short* __restrict__ qT,
    float* __restrict__ opart, float* __restrict__ lbuf)
{
    __shared__ short kt[64][72];       // [k-row][d]
    __shared__ short vt[64][72];       // [h][k-col]
    __shared__ short plT[4][16][72];   // per-wave P^T as [q][k]

    const int tid  = threadIdx.x;
    const int w    = tid >> 6;
    const int lane = tid & 63;
    const int quad = lane >> 4;
    const int lr   = lane & 15;
    const int b    = blockIdx.y;
    const int q0   = blockIdx.x * 64;
    const int z    = blockIdx.z;
    const int slice = S_ / gridDim.z;
    const int kbase = z * slice;
    const short* qb  = q  + (size_t)b * S_ * H_;
    const short* qTb = qT + (size_t)b * H_ * SP_;

    // resident Q B-frags: B[k=d=quad*8+j][n=q=lr]
    bf16x8 qB[2];
    {
        const short* qr = qb + (size_t)(q0 + w * 16 + lr) * H_;
        qB[0] = *(const bf16x8*)(qr + quad * 8);
        qB[1] = *(const bf16x8*)(qr + 32 + quad * 8);
    }

    f32x4 o[4];
#pragma unroll
    for (int mt = 0; mt < 4; ++mt) o[mt] = (f32x4){0.f, 0.f, 0.f, 0.f};
    float lacc = 0.0f;

    // staging: thread -> row srow, 32B at scol (fully coalesced)
    const int srow = tid >> 2;
    const int scol = (tid & 3) * 16;
    const short* gk = qb  + (size_t)(kbase + srow) * H_ + scol;
    const short* gv = qTb + (size_t)srow * SP_ + kbase + scol;

    uint4 pk0 = *(const uint4*)gk, pk1 = *(const uint4*)(gk + 8);
    uint4 pv0 = *(const uint4*)gv, pv1 = *(const uint4*)(gv + 8);

    const int iters = slice >> 6;
    for (int it = 0; it < iters; ++it) {
        __syncthreads();               // prev tiles consumed
        *(uint4*)&kt[srow][scol]     = pk0;
        *(uint4*)&kt[srow][scol + 8] = pk1;
        *(uint4*)&vt[srow][scol]     = pv0;
        *(uint4*)&vt[srow][scol + 8] = pv1;
        __syncthreads();               // staging visible
        if (it + 1 < iters) {
            gk += (size_t)64 * H_;
            gv += 64;
            pk0 = *(const uint4*)gk; pk1 = *(const uint4*)(gk + 8);
            pv0 = *(const uint4*)gv; pv1 = *(const uint4*)(gv + 8);
        }

        // ---- S^T = K Q^T ----
        f32x4 s[4];
#pragma unroll
        for (int mt = 0; mt < 4; ++mt) s[mt] = (f32x4){0.f, 0.f, 0.f, 0.f};
#pragma unroll
        for (int c = 0; c < 2; ++c)
#pragma unroll
            for (int mt = 0; mt < 4; ++mt) {
                const bf16x8 a = *(const bf16x8*)&kt[mt * 16 + lr][c * 32 + quad * 8];
                s[mt] = __builtin_amdgcn_mfma_f32_16x16x32_bf16(a, qB[c], s[mt], 0, 0, 0);
            }

        // ---- P^T = exp(S^T * scale); packed b64 stores; lane row-sum ----
#pragma unroll
        for (int mt = 0; mt < 4; ++mt) {
            bf16x4 pb;
#pragma unroll
            for (int i = 0; i < 4; ++i) {
                const float p = __expf(s[mt][i] * SCALE_);
                lacc += p;
                pb[i] = f2bf(p);
            }
            *(bf16x4*)&plT[w][lr][mt * 16 + quad * 4] = pb;
        }

        // ---- O += V^T-as-A  x  P^T-as-B ----
#pragma unroll
        for (int c = 0; c < 2; ++c) {
            const bf16x8 pB = *(const bf16x8*)&plT[w][lr][c * 32 + quad * 8];
#pragma unroll
            for (int mt = 0; mt < 4; ++mt) {
                const bf16x8 a = *(const bf16x8*)&vt[mt * 16 + lr][c * 32 + quad * 8];
                o[mt] = __builtin_amdgcn_mfma_f32_16x16x32_bf16(a, pB, o[mt], 0, 0, 0);
            }
        }
    }

    // ---- finish l: sum across the 4 quads (k-coverage), lane q=lr ----
    lacc += __shfl_xor(lacc, 16, 64);
    lacc += __shfl_xor(lacc, 32, 64);

    // ---- write partials: O[q=lr][h=mt*16+quad*4+i] ----
    float* ob = opart + (((size_t)z * B_ + b) * S_ + q0 + w * 16 + lr) * H_;
#pragma unroll
    for (int mt = 0; mt < 4; ++mt)
        *(f32x4*)(ob + mt * 16 + quad * 4) = o[mt];
    if (quad == 0)
        lbuf[((size_t)z * B_ + b) * S_ + q0 + w * 16 + lr] = lacc;
}

// ---------------------------------------------------------------------------
// combine: out[row][:] = sum_z opart[z][row][:] / sum_z lbuf[z][row]
// ---------------------------------------------------------------------------
__global__ __launch_bounds__(256) void combine_kernel(
    const float* __restrict__ opart, const float* __restrict__ lbuf,
    float* __restrict__ out, int nsplit)
{
    const int t   = blockIdx.x * 256 + threadIdx.x;   // 262144
    const int row = t >> 4;
    const int c4  = (t & 15) * 4;
    f32x4 acc = (f32x4){0.f, 0.f, 0.f, 0.f};
    float l = 0.0f;
    for (int z = 0; z < nsplit; ++z) {
        const f32x4 v = *(const f32x4*)(opart + ((size_t)z * (B_ * S_) + row) * H_ + c4);
        acc[0] += v[0]; acc[1] += v[1]; acc[2] += v[2]; acc[3] += v[3];
        l += lbuf[(size_t)z * (B_ * S_) + row];
    }
    const float r = 1.0f / l;
    acc[0] *= r; acc[1] *= r; acc[2] *= r; acc[3] *= r;
    *(f32x4*)(out + (size_t)row * H_ + c4) = acc;
}

extern "C" void kernel_launch(void* const* d_in, const int* in_sizes, int n_in,
                              void* d_out, int out_size, void* d_ws, size_t ws_size,
                              hipStream_t stream) {
    const float* x  = (const float*)d_in[0];   // [4,4096,1024] f32
    const float* wq = (const float*)d_in[1];   // [64,1024] f32
    float* out = (float*)d_out;                // [4,4096,64] f32

    // ws layout (bytes)
    const size_t off_qT  = 2097152;                               // q: 2 MiB
    const size_t off_wqb = off_qT + (size_t)B_ * H_ * SP_ * 2;    // qT padded
    const size_t off_op  = off_wqb + (size_t)H_ * WP_ * 2;        // wqb padded
    short* qbuf = (short*)d_ws;
    short* qT   = (short*)((char*)d_ws + off_qT);
    short* wqb  = (short*)((char*)d_ws + off_wqb);

    // pick split-K factor that fits the workspace
    const size_t per_split = (size_t)B_ * S_ * H_ * 4 + (size_t)B_ * S_ * 4;
    int nsplit = 4;
    if (ws_size < off_op + 4 * per_split) nsplit = 1;
    float* opart = (float*)((char*)d_ws + off_op);
    float* lbuf  = (float*)((char*)d_ws + off_op + (size_t)nsplit * B_ * S_ * H_ * 4);

    winit_kernel<<<dim3(32), dim3(256), 0, stream>>>(wq, wqb);
    qproj_mfma<<<dim3((B_ * S_) / 16), dim3(256), 0, stream>>>(x, wqb, qbuf, qT);
    flash_mfma<<<dim3(S_ / 64, B_, nsplit), dim3(256), 0, stream>>>(qbuf, qT, opart, lbuf);
    combine_kernel<<<dim3(1024), dim3(256), 0, stream>>>(opart, lbuf, out, nsplit);
}